// Round 5
// baseline (691.217 us; speedup 1.0000x reference)
//
#include <hip/hip_runtime.h>

#define TT 216
#define BB 16384
#define LOG2E 1.44269504088896340736f

typedef _Float16 h16;
typedef _Float16 half8 __attribute__((ext_vector_type(8)));
typedef float f32x4 __attribute__((ext_vector_type(4)));
// Vector types get char-TBAA in clang (alias everything) -> safe for LDS type
// punning. Scalar puns (unsigned long long) carry their own TBAA tag and get
// reordered across _Float16 stores (round-2 bug) -- never use scalar puns.

// Raw barrier: drains LDS only (lgkmcnt), NOT vmcnt. __syncthreads() emits
// s_waitcnt vmcnt(0) before s_barrier, which kills every in-flight global
// prefetch once per step (the round-4 critical path). The "memory" clobber is
// the compiler fence; register-destined global loads get fine-grained vmcnt
// waits at their uses, 2-3 steps downstream.
#define RAW_BAR() asm volatile("s_waitcnt lgkmcnt(0)\n\ts_barrier" ::: "memory")

__device__ __forceinline__ float rcp_f(float v) { return __builtin_amdgcn_rcpf(v); }
__device__ __forceinline__ float ex2(float v)   { return __builtin_amdgcn_exp2f(v); }

// Gate preactivations arrive PRE-SCALED: pi,pf,po = -log2e*(preact), pg = 2*log2e*(preact).
// State cs = 2*log2e * c (pre-scaled cell state).
// sigmoid(i) = 1/(1+2^pi); tanh(g) = (Eg-2)/Eg, Eg = 1+2^pg.
// cs' = cs/Ef + 2L*(Eg-2)/(Ei*Eg) -> single rcp via common denominator.
// h = (Ec-2)/(Eo*Ec), Ec = 1+2^min(cs',60)  (clamp: keeps Eo*Ec finite).
__device__ __forceinline__ float lstm_up(float pi, float pf, float pg, float po, float& cs)
{
    float ei = ex2(pi), ef = ex2(pf), eg = ex2(pg), eo = ex2(po);
    float Ei = 1.f + ei, Ef = 1.f + ef, Eg = 1.f + eg, Eo = 1.f + eo;
    float EiEg = Ei * Eg;
    float G = fmaf(2.f * LOG2E, Eg, -4.f * LOG2E);   // 2L*(Eg-2)
    float N = fmaf(cs, EiEg, Ef * G);
    cs = N * rcp_f(Ef * EiEg);
    float pc = fminf(cs, 60.f);
    float Ec = 1.f + ex2(pc);
    return (Ec - 2.f) * rcp_f(Eo * Ec);
}

// ---------------- weight prep: fp32 -> fp16, fragment-ready, exp2-prescaled, bias-in-K ----
__global__ void prep_kernel(
    const float* __restrict__ Wih_f, const float* __restrict__ Whh_f,
    const float* __restrict__ bih_f, const float* __restrict__ bhh_f,
    const float* __restrict__ Wih_b, const float* __restrict__ Whh_b,
    const float* __restrict__ bih_b, const float* __restrict__ bhh_b,
    const float* __restrict__ Wih_m, const float* __restrict__ Whh_m,
    const float* __restrict__ bih_m, const float* __restrict__ bhh_m,
    h16* __restrict__ W1f, h16* __restrict__ W1b, h16* __restrict__ W2)
{
    int gtid = blockIdx.x * blockDim.x + threadIdx.x;
    int gs = gridDim.x * blockDim.x;
    // small LSTMs: W1[n=64][k=32]: k<8 x, 8..23 h, 24 bias (X col24==1), 25..31 zero
    for (int idx = gtid; idx < 64 * 32; idx += gs) {
        int n = idx >> 5, k = idx & 31;
        float a = ((n >> 4) == 2) ? 2.f * LOG2E : -LOG2E;
        float vf = 0.f, vb = 0.f;
        if (k < 8)        { vf = Wih_f[n * 8 + k];       vb = Wih_b[n * 8 + k]; }
        else if (k < 24)  { vf = Whh_f[n * 16 + k - 8];  vb = Whh_b[n * 16 + k - 8]; }
        else if (k == 24) { vf = bih_f[n] + bhh_f[n];    vb = bih_b[n] + bhh_b[n]; }
        W1f[idx] = (h16)(vf * a);
        W1b[idx] = (h16)(vb * a);
    }
    // middle LSTM: W2[n=256][k=128]: k<32 [hs_f|hs_b], 32..95 h2, 96 bias, 97..127 zero
    for (int idx = gtid; idx < 256 * 128; idx += gs) {
        int n = idx >> 7, k = idx & 127;
        float a = ((n >> 6) == 2) ? 2.f * LOG2E : -LOG2E;
        float v = 0.f;
        if (k < 32)       v = Wih_m[n * 32 + k];
        else if (k < 96)  v = Whh_m[n * 64 + k - 32];
        else if (k == 96) v = bih_m[n] + bhh_m[n];
        W2[idx] = (h16)(v * a);
    }
}

// ---------------- small LSTMs (fwd + bwd), 4-wave gate-split, 32 waves/CU ----------------
// grid = 2048 blocks (2 dirs x 1024 batch-tiles of 16). Block = 4 waves; wave g computes
// gate-plane g (1 MFMA), C exchanged via padded LDS; each lane does 1 lstm_up.
// hs layout: [T][B][16] fp16; stored one step lagged from the stable X buffer.
__global__ __launch_bounds__(256, 8) void small_lstm_kernel(
    const float* __restrict__ x,
    const float* __restrict__ h0f, const float* __restrict__ c0f,
    const float* __restrict__ h0b, const float* __restrict__ c0b,
    const h16* __restrict__ W1f, const h16* __restrict__ W1b,
    h16* __restrict__ hsf, h16* __restrict__ hsb)
{
    __shared__ __attribute__((aligned(16))) h16 Xs[2][16][40];   // k: 0..7 x, 8..23 h, 24 one, 25..31 zero
    __shared__ __attribute__((aligned(16))) float Cx[4][16][20]; // [gate][unit][batch] (+pad)

    const int tid = threadIdx.x;
    const int wv = tid >> 6, lane = tid & 63, col = lane & 15, q = lane >> 4;
    const int dir = blockIdx.x & 1;
    const int base = (blockIdx.x >> 1) * 16;

    const float* h0 = dir ? h0b : h0f;
    const float* c0 = dir ? c0b : c0f;
    const h16* W1   = dir ? W1b : W1f;
    h16* hs = dir ? hsb : hsf;

    // wave's gate-plane B fragment (bias folded in at k=24)
    half8 bf = *(const half8*)(W1 + (wv * 16 + col) * 32 + q * 8);

    const int eu = wv * 4 + q, eb = col;   // this lane's (unit, batch) element in phase 2
    float cs = c0[(size_t)(base + eb) * 16 + eu] * (2.f * LOG2E);

    // init pad cols 24..31 (24 = bias-one) in both buffers
    {
        int buf = tid >> 7, row = (tid >> 3) & 15, cc = 24 + (tid & 7);
        Xs[buf][row][cc] = (cc == 24) ? (h16)1.f : (h16)0.f;
    }
    // h0 -> Xs[0] h-region
    {
        int b = tid >> 4, u = tid & 15;
        Xs[0][b][8 + u] = (h16)h0[(size_t)(base + b) * 16 + u];
    }
    // x staging (threads < 128), 2-deep register pipeline
    const int xrow = (tid >> 3) & 15, xk = tid & 7;
    float xr1 = 0.f, xr2 = 0.f;
    if (tid < 128) {
        int t0 = dir ? (TT - 1) : 0;
        int t1 = dir ? (TT - 2) : 1;
        int t2 = dir ? (TT - 3) : 2;
        Xs[0][xrow][xk] = (h16)x[((size_t)t0 * BB + base + xrow) * 8 + xk];
        xr1 = x[((size_t)t1 * BB + base + xrow) * 8 + xk];
        xr2 = x[((size_t)t2 * BB + base + xrow) * 8 + xk];
    }
    RAW_BAR();

    const int sb = tid >> 4, su = tid & 15;   // hs-store mapping (contiguous across tid)
    for (int s = 0; s < TT; ++s) {
        const int cur = s & 1, nxt = cur ^ 1;
        // phase 1: Xs[cur] is stable (all writes target Xs[nxt]) -> store hs(s-1)
        if (s > 0) {
            int tp = dir ? (TT - s) : (s - 1);
            hs[((size_t)tp * BB + base + sb) * 16 + su] = Xs[cur][sb][8 + su];
        }
        half8 af = *(const half8*)&Xs[cur][col][q * 8];
        f32x4 z = {0.f, 0.f, 0.f, 0.f};
        z = __builtin_amdgcn_mfma_f32_16x16x32_f16(af, bf, z, 0, 0, 0);
        *(f32x4*)&Cx[wv][col][q * 4] = z;     // C-layout: rows=batch(q*4+r), col=unit
        if (tid < 128 && s < TT - 1) {        // x for step s+1 into Xs[nxt]
            Xs[nxt][xrow][xk] = (h16)xr1;
            xr1 = xr2;
            int sl = (s + 3 < TT) ? (s + 3) : (TT - 1);
            int tl = dir ? (TT - 1 - sl) : sl;
            xr2 = x[((size_t)tl * BB + base + xrow) * 8 + xk];
        }
        RAW_BAR();   // Cx ready (LDS-only drain; x prefetch stays in flight)
        float h = lstm_up(Cx[0][eu][eb], Cx[1][eu][eb], Cx[2][eu][eb], Cx[3][eu][eb], cs);
        Xs[nxt][eb][8 + eu] = (h16)h;
        RAW_BAR();   // Xs[nxt] ready for next step
    }
    {   // hs(TT-1): final h sits in Xs[TT&1] = Xs[0]
        int tp = dir ? 0 : (TT - 1);
        hs[((size_t)tp * BB + base + sb) * 16 + su] = Xs[0][sb][8 + su];
    }
}

// ---------------- middle LSTM + dense, 16-batch blocks, K=128 (bias in k=96) -------------
// block = 256 (4 waves): wave w handles units [16w,16w+16) for all 4 gates (16 MFMA/step).
// X[16][128] = [hs_f|hs_b|h2|bias-one|zeros] fp16, double-buffered. One barrier per step.
// Dense out(t-1) = wd . h2(t-1) = 2 extra MFMA on wave 3 over X(t) k=32..95.
__global__ __launch_bounds__(256, 4) void mid_lstm_kernel(
    const h16* __restrict__ hsf, const h16* __restrict__ hsb,
    const float* __restrict__ h0m, const float* __restrict__ c0m,
    const h16* __restrict__ W2,
    const float* __restrict__ Wd, const float* __restrict__ bdp,
    float* __restrict__ out)
{
    __shared__ __attribute__((aligned(16))) h16 Xs[2][16][136];
    __shared__ float outbuf[16][55];

    const int tid = threadIdx.x;
    const int base = blockIdx.x * 16;
    const int wv = tid >> 6, lane = tid & 63, col = lane & 15, q = lane >> 4;

    half8 bfr[4][4];
#pragma unroll
    for (int p = 0; p < 4; ++p) {
        int n = p * 64 + wv * 16 + col;
#pragma unroll
        for (int kt = 0; kt < 4; ++kt)
            bfr[p][kt] = *(const half8*)(W2 + (size_t)n * 128 + kt * 32 + q * 8);
    }
    half8 dfr[2];   // dense B-fragment: column 0 = wd over k in [32,96)
#pragma unroll
    for (int kt = 0; kt < 2; ++kt)
#pragma unroll
        for (int j = 0; j < 8; ++j)
            dfr[kt][j] = (col == 0) ? (h16)Wd[kt * 32 + q * 8 + j] : (h16)0.f;
    const float bdv = bdp[0];

    float cs[4];
#pragma unroll
    for (int r = 0; r < 4; ++r)
        cs[r] = c0m[(size_t)(base + q * 4 + r) * 64 + wv * 16 + col] * (2.f * LOG2E);

    // init cols 96..127 (96 = bias-one) in both buffers
    {
        int buf = tid >> 7, row = (tid >> 3) & 15, cc = 96 + (tid & 7) * 4;
        h16* d = &Xs[buf][row][cc];
        d[0] = ((tid & 7) == 0) ? (h16)1.f : (h16)0.f;
        d[1] = (h16)0.f; d[2] = (h16)0.f; d[3] = (h16)0.f;
    }
    const h16* hsrc = (wv == 1) ? hsb : hsf;
    const int srow = lane >> 1, su8 = (lane & 1) * 8;
    // initial staging: hs(0) + h0m into Xs[0]
    if (wv < 2 && lane < 32) {
        uint4 v = *(const uint4*)(hsrc + ((size_t)0 * BB + base + srow) * 16 + su8);
        *(uint4*)&Xs[0][srow][wv * 16 + su8] = v;
    }
    {
        int row = tid >> 4, u4 = (tid & 15) * 4;
        float4 v = *(const float4*)(h0m + (size_t)(base + row) * 64 + u4);
        h16* d = &Xs[0][row][32 + u4];
        d[0] = (h16)v.x; d[1] = (h16)v.y; d[2] = (h16)v.z; d[3] = (h16)v.w;
    }
    // hs register pipeline (2 steps deep) on waves 0,1
    uint4 ra, rb;
    if (wv < 2 && lane < 32) {
        ra = *(const uint4*)(hsrc + ((size_t)1 * BB + base + srow) * 16 + su8);
        rb = *(const uint4*)(hsrc + ((size_t)2 * BB + base + srow) * 16 + su8);
    }
    RAW_BAR();

    for (int t = 0; t < TT; ++t) {
        const int cur = t & 1, nxt = cur ^ 1;
        if (wv < 2 && lane < 32) {
            if (t < TT - 1)
                *(uint4*)&Xs[nxt][srow][wv * 16 + su8] = ra;   // hs(t+1)
            ra = rb;
            int tl = (t + 3 < TT) ? (t + 3) : (TT - 1);
            rb = *(const uint4*)(hsrc + ((size_t)tl * BB + base + srow) * 16 + su8);
        }
        half8 af[4];
#pragma unroll
        for (int kt = 0; kt < 4; ++kt)
            af[kt] = *(const half8*)&Xs[cur][col][kt * 32 + q * 8];
        // dense for out(t-1): X(t) k=32..95 holds h2(t-1)
        if (wv == 3 && t > 0) {
            f32x4 z = {0.f, 0.f, 0.f, 0.f};
            z = __builtin_amdgcn_mfma_f32_16x16x32_f16(af[1], dfr[0], z, 0, 0, 0);
            z = __builtin_amdgcn_mfma_f32_16x16x32_f16(af[2], dfr[1], z, 0, 0, 0);
            if (col == 0) {
                int tc = (t - 1) % 54;
#pragma unroll
                for (int r = 0; r < 4; ++r)
                    outbuf[q * 4 + r][tc] = z[r] + bdv;
            }
        }
        f32x4 acc[4];
#pragma unroll
        for (int p = 0; p < 4; ++p) {
            f32x4 z = {0.f, 0.f, 0.f, 0.f};
            z = __builtin_amdgcn_mfma_f32_16x16x32_f16(af[0], bfr[p][0], z, 0, 0, 0);
            z = __builtin_amdgcn_mfma_f32_16x16x32_f16(af[1], bfr[p][1], z, 0, 0, 0);
            z = __builtin_amdgcn_mfma_f32_16x16x32_f16(af[2], bfr[p][2], z, 0, 0, 0);
            z = __builtin_amdgcn_mfma_f32_16x16x32_f16(af[3], bfr[p][3], z, 0, 0, 0);
            acc[p] = z;
        }
#pragma unroll
        for (int r = 0; r < 4; ++r) {
            float h = lstm_up(acc[0][r], acc[1][r], acc[2][r], acc[3][r], cs[r]);
            Xs[nxt][q * 4 + r][32 + wv * 16 + col] = (h16)h;
        }
        if (t > 0 && (t % 54) == 0) {   // flush out(t-54 .. t-1)
            RAW_BAR();
            int off = t - 54;
            for (int idx = tid; idx < 16 * 54; idx += 256) {
                int row = idx / 54, cc = idx - row * 54;
                out[(size_t)(base + row) * TT + off + cc] = outbuf[row][cc];
            }
        }
        RAW_BAR();
    }
    // epilogue: out(215) from Xs[0] (h2(215) staged there at t=215)
    if (wv == 3) {
        half8 a1 = *(const half8*)&Xs[0][col][32 + q * 8];
        half8 a2 = *(const half8*)&Xs[0][col][64 + q * 8];
        f32x4 z = {0.f, 0.f, 0.f, 0.f};
        z = __builtin_amdgcn_mfma_f32_16x16x32_f16(a1, dfr[0], z, 0, 0, 0);
        z = __builtin_amdgcn_mfma_f32_16x16x32_f16(a2, dfr[1], z, 0, 0, 0);
        if (col == 0)
#pragma unroll
            for (int r = 0; r < 4; ++r)
                outbuf[q * 4 + r][53] = z[r] + bdv;
    }
    RAW_BAR();
    for (int idx = tid; idx < 16 * 54; idx += 256) {
        int row = idx / 54, cc = idx - row * 54;
        out[(size_t)(base + row) * TT + 162 + cc] = outbuf[row][cc];
    }
}

extern "C" void kernel_launch(void* const* d_in, const int* in_sizes, int n_in,
                              void* d_out, int out_size, void* d_ws, size_t ws_size,
                              hipStream_t stream)
{
    const float* x     = (const float*)d_in[0];
    const float* h0f   = (const float*)d_in[1];
    const float* c0f   = (const float*)d_in[2];
    const float* h0b   = (const float*)d_in[3];
    const float* c0b   = (const float*)d_in[4];
    const float* h0m   = (const float*)d_in[5];
    const float* c0m   = (const float*)d_in[6];
    const float* Wih_f = (const float*)d_in[7];
    const float* Whh_f = (const float*)d_in[8];
    const float* bih_f = (const float*)d_in[9];
    const float* bhh_f = (const float*)d_in[10];
    const float* Wih_b = (const float*)d_in[11];
    const float* Whh_b = (const float*)d_in[12];
    const float* bih_b = (const float*)d_in[13];
    const float* bhh_b = (const float*)d_in[14];
    const float* Wih_m = (const float*)d_in[15];
    const float* Whh_m = (const float*)d_in[16];
    const float* bih_m = (const float*)d_in[17];
    const float* bhh_m = (const float*)d_in[18];
    const float* Wd    = (const float*)d_in[19];
    const float* bd    = (const float*)d_in[20];

    char* ws = (char*)d_ws;
    h16* W1f = (h16*)(ws + 0);        // 64*32*2    = 4096
    h16* W1b = (h16*)(ws + 4096);     // 4096
    h16* W2  = (h16*)(ws + 8192);     // 256*128*2  = 65536
    h16* hsf = (h16*)(ws + 73728);                               // [T][B][16] fp16
    h16* hsb = (h16*)(ws + 73728 + (size_t)TT * BB * 16 * 2);    // [T][B][16] fp16

    prep_kernel<<<64, 256, 0, stream>>>(Wih_f, Whh_f, bih_f, bhh_f,
                                        Wih_b, Whh_b, bih_b, bhh_b,
                                        Wih_m, Whh_m, bih_m, bhh_m,
                                        W1f, W1b, W2);
    small_lstm_kernel<<<2048, 256, 0, stream>>>(x, h0f, c0f, h0b, c0b,
                                                W1f, W1b, hsf, hsb);
    mid_lstm_kernel<<<1024, 256, 0, stream>>>(hsf, hsb, h0m, c0m, W2,
                                              Wd, bd, (float*)d_out);
}